// Round 4
// baseline (669.960 us; speedup 1.0000x reference)
//
#include <hip/hip_runtime.h>
#include <hip/hip_bf16.h>
#include <cstdint>

#define N_NODESC  102400
#define N_EDGESC  1638400
#define NUM_GRAPHS 128
#define NPG       800
#define HID       128
#define BN_EPS    1e-5f

typedef short short8 __attribute__((ext_vector_type(8)));
typedef float f32x4  __attribute__((ext_vector_type(4)));

__device__ __forceinline__ unsigned short f2bf(float f){
    union { __hip_bfloat16 h; unsigned short u; } cv;
    cv.h = __float2bfloat16(f);
    return cv.u;
}
__device__ __forceinline__ float bflo(unsigned int g){ return __uint_as_float(g << 16); }
__device__ __forceinline__ float bfhi(unsigned int g){ return __uint_as_float(g & 0xffff0000u); }
__device__ __forceinline__ float bfu(unsigned short u){ return __uint_as_float(((unsigned int)u) << 16); }

// ----------------- CSR build -----------------
__global__ void k_count(const int* __restrict__ ei, int* __restrict__ deg){
    int e = blockIdx.x*blockDim.x + threadIdx.x;
    if (e < N_EDGESC) atomicAdd(&deg[ei[N_EDGESC + e]], 1);
}

__global__ __launch_bounds__(1024) void k_scan_a(const int* __restrict__ deg, int* __restrict__ row_ptr,
                                                 float* __restrict__ dinv, int* __restrict__ chunkTot){
    __shared__ int sh[1024];
    int t = threadIdx.x;
    int i = blockIdx.x*1024 + t;
    int v = deg[i];
    dinv[i] = rsqrtf((float)(v + 1));   // +1 self loop
    sh[t] = v;
    __syncthreads();
    for (int off = 1; off < 1024; off <<= 1){
        int add = (t >= off) ? sh[t - off] : 0;
        __syncthreads();
        sh[t] += add;
        __syncthreads();
    }
    row_ptr[i] = sh[t] - v;
    if (t == 1023) chunkTot[blockIdx.x] = sh[t];
}

__global__ __launch_bounds__(128) void k_scan_b(const int* __restrict__ chunkTot, int* __restrict__ chunkOff,
                                                int* __restrict__ row_ptr){
    __shared__ int sh[128];
    int t = threadIdx.x;
    int v = (t < 100) ? chunkTot[t] : 0;
    sh[t] = v;
    __syncthreads();
    for (int off = 1; off < 128; off <<= 1){
        int add = (t >= off) ? sh[t - off] : 0;
        __syncthreads();
        sh[t] += add;
        __syncthreads();
    }
    if (t < 100) chunkOff[t] = sh[t] - v;
    if (t == 0)  row_ptr[N_NODESC] = N_EDGESC;
}

__global__ __launch_bounds__(1024) void k_scan_c(int* __restrict__ row_ptr, const int* __restrict__ chunkOff){
    int i = blockIdx.x*1024 + threadIdx.x;
    row_ptr[i] += chunkOff[blockIdx.x];
}

__global__ void k_scatter(const int* __restrict__ ei, const int* __restrict__ row_ptr,
                          int* __restrict__ cursor, int* __restrict__ srcS){
    int e = blockIdx.x*blockDim.x + threadIdx.x;
    if (e < N_EDGESC){
        int s = ei[e];
        int d = ei[N_EDGESC + e];
        int pos = row_ptr[d] + atomicAdd(&cursor[d], 1);
        srcS[pos] = s;
    }
}

// ----------------- W0^T in bf16 -----------------
__global__ __launch_bounds__(256) void k_prepw0(const float* __restrict__ W, unsigned short* __restrict__ Wt){
    int idx = blockIdx.x*256 + threadIdx.x;          // 16384 elements
    int n = idx & 127, k = idx >> 7;
    Wt[n*128 + k] = f2bf(W[k*128 + n]);
}

// ----------------- MFMA bf16 GEMM: Hd = bf16(dinv[row] * (X @ W + biasv)) -----------------
// M=102400, N=K=128. 4 waves/block, wave computes 16 rows x 128 cols. No LDS.
template<int F32IN>
__global__ __launch_bounds__(256) void k_gemm_mfma(const void* __restrict__ Xin,
        const unsigned short* __restrict__ Wt, const float* __restrict__ biasv,
        const float* __restrict__ dinv, unsigned short* __restrict__ H){
    int l   = threadIdx.x & 63;
    int wid = threadIdx.x >> 6;
    int R   = blockIdx.x*64 + wid*16;
    int r0  = l & 15;          // A-row / B-col / D-col within fragment
    int kg  = l >> 4;          // 8-wide k group
    short8 a[4];
    if (F32IN){
        const float* X = (const float*)Xin;
        #pragma unroll
        for (int kk = 0; kk < 4; kk++){
            const float* p = X + (size_t)(R + r0)*HID + kk*32 + kg*8;
            float4 u = *(const float4*)p;
            float4 v = *(const float4*)(p + 4);
            short8 t;
            t[0]=(short)f2bf(u.x); t[1]=(short)f2bf(u.y); t[2]=(short)f2bf(u.z); t[3]=(short)f2bf(u.w);
            t[4]=(short)f2bf(v.x); t[5]=(short)f2bf(v.y); t[6]=(short)f2bf(v.z); t[7]=(short)f2bf(v.w);
            a[kk] = t;
        }
    } else {
        const unsigned short* X = (const unsigned short*)Xin;
        #pragma unroll
        for (int kk = 0; kk < 4; kk++)
            a[kk] = *(const short8*)(X + (size_t)(R + r0)*HID + kk*32 + kg*8);
    }
    f32x4 acc[8];
    #pragma unroll
    for (int i = 0; i < 8; i++) acc[i] = (f32x4)(0.f);
    #pragma unroll
    for (int kk = 0; kk < 4; kk++){
        #pragma unroll
        for (int nf = 0; nf < 8; nf++){
            short8 b = *(const short8*)(Wt + (size_t)(nf*16 + r0)*HID + kk*32 + kg*8);
            acc[nf] = __builtin_amdgcn_mfma_f32_16x16x32_bf16(a[kk], b, acc[nf], 0, 0, 0);
        }
    }
    float bv[8];
    #pragma unroll
    for (int nf = 0; nf < 8; nf++) bv[nf] = biasv[nf*16 + r0];
    #pragma unroll
    for (int r = 0; r < 4; r++){
        int row = R + kg*4 + r;
        float di = dinv[row];
        #pragma unroll
        for (int nf = 0; nf < 8; nf++)
            H[(size_t)row*HID + nf*16 + r0] = f2bf(di * (acc[nf][r] + bv[nf]));
    }
}

// --------- aggregation + relu + fused BN stats; 2 edges per gather (uint2/lane), pre-scaled rows ---------
// OUT[n] = relu( dinv[n] * (sum_e Hd[src_e] + Hd[n]) + b )
__global__ __launch_bounds__(256) void k_agg(const uint2* __restrict__ Hb2, const int* __restrict__ row_ptr,
                                             const int* __restrict__ srcS, const float* __restrict__ dinv,
                                             const float* __restrict__ bconv,
                                             uint2* __restrict__ OUT2, float* __restrict__ sum,
                                             float* __restrict__ sumsq){
    int lane = threadIdx.x & 63;
    int half = lane >> 5;          // 0: edge set A, 1: edge set B
    int lc   = lane & 31;          // channel quad index (ch 4lc..4lc+3)
    int w    = threadIdx.x >> 6;
    int wave = blockIdx.x*4 + w;
    int nw   = gridDim.x*4;
    float4 bc = ((const float4*)bconv)[lc];
    float sx0=0,sx1=0,sx2=0,sx3=0,sq0=0,sq1=0,sq2=0,sq3=0;
    for (int n = wave; n < N_NODESC; n += nw){
        int e0 = row_ptr[n], e1 = row_ptr[n+1];
        float a0=0,a1=0,a2=0,a3=0;
        int e = e0;
        // 4 pair-gathers = 8 edges in flight
        for (; e + 8 <= e1; e += 8){
            int s0 = srcS[e     + half];
            int s1 = srcS[e + 2 + half];
            int s2 = srcS[e + 4 + half];
            int s3 = srcS[e + 6 + half];
            uint2 g0 = Hb2[(size_t)s0*32 + lc];
            uint2 g1 = Hb2[(size_t)s1*32 + lc];
            uint2 g2 = Hb2[(size_t)s2*32 + lc];
            uint2 g3 = Hb2[(size_t)s3*32 + lc];
            a0 += bflo(g0.x); a1 += bfhi(g0.x); a2 += bflo(g0.y); a3 += bfhi(g0.y);
            a0 += bflo(g1.x); a1 += bfhi(g1.x); a2 += bflo(g1.y); a3 += bfhi(g1.y);
            a0 += bflo(g2.x); a1 += bfhi(g2.x); a2 += bflo(g2.y); a3 += bfhi(g2.y);
            a0 += bflo(g3.x); a1 += bfhi(g3.x); a2 += bflo(g3.y); a3 += bfhi(g3.y);
        }
        for (; e + 2 <= e1; e += 2){
            int s = srcS[e + half];
            uint2 g = Hb2[(size_t)s*32 + lc];
            a0 += bflo(g.x); a1 += bfhi(g.x); a2 += bflo(g.y); a3 += bfhi(g.y);
        }
        {   // combined tail + self-loop gather: half0 = tail edge (or self), half1 = self (or zero row)
            int s;
            if (e < e1) s = half ? n : srcS[e];
            else        s = half ? N_NODESC : n;
            uint2 g = Hb2[(size_t)s*32 + lc];
            a0 += bflo(g.x); a1 += bfhi(g.x); a2 += bflo(g.y); a3 += bfhi(g.y);
        }
        // combine the two half-wave edge sets
        a0 += __shfl_xor(a0, 32);
        a1 += __shfl_xor(a1, 32);
        a2 += __shfl_xor(a2, 32);
        a3 += __shfl_xor(a3, 32);
        if (half == 0){
            float dn = dinv[n];
            a0 = fmaxf(fmaf(a0, dn, bc.x), 0.f);
            a1 = fmaxf(fmaf(a1, dn, bc.y), 0.f);
            a2 = fmaxf(fmaf(a2, dn, bc.z), 0.f);
            a3 = fmaxf(fmaf(a3, dn, bc.w), 0.f);
            uint2 o;
            o.x = ((unsigned int)f2bf(a1) << 16) | (unsigned int)f2bf(a0);
            o.y = ((unsigned int)f2bf(a3) << 16) | (unsigned int)f2bf(a2);
            OUT2[(size_t)n*32 + lc] = o;
            sx0 += a0; sq0 = fmaf(a0,a0,sq0);
            sx1 += a1; sq1 = fmaf(a1,a1,sq1);
            sx2 += a2; sq2 = fmaf(a2,a2,sq2);
            sx3 += a3; sq3 = fmaf(a3,a3,sq3);
        }
    }
    __shared__ float shs[4][128];
    __shared__ float shq[4][128];
    if (half == 0){
        shs[w][4*lc+0] = sx0; shs[w][4*lc+1] = sx1; shs[w][4*lc+2] = sx2; shs[w][4*lc+3] = sx3;
        shq[w][4*lc+0] = sq0; shq[w][4*lc+1] = sq1; shq[w][4*lc+2] = sq2; shq[w][4*lc+3] = sq3;
    }
    __syncthreads();
    int t = threadIdx.x;
    if (t < 128){
        atomicAdd(&sum[t],   shs[0][t] + shs[1][t] + shs[2][t] + shs[3][t]);
        atomicAdd(&sumsq[t], shq[0][t] + shq[1][t] + shq[2][t] + shq[3][t]);
    }
}

// ----------------- BN finalize + fold into next W (emits transposed bf16 W' + bias) -----------------
__global__ __launch_bounds__(128) void k_finalize(const float* __restrict__ sum, const float* __restrict__ sumsq,
                                                  const float* __restrict__ gamma, const float* __restrict__ beta,
                                                  const float* __restrict__ Wnext, float* __restrict__ A,
                                                  float* __restrict__ B, unsigned short* __restrict__ WpT,
                                                  float* __restrict__ biasv, int hasNext){
    __shared__ float Ash[128], Bsh[128];
    int c = threadIdx.x;
    const float invN = 1.0f / (float)N_NODESC;
    float mu  = sum[c] * invN;
    float var = sumsq[c] * invN - mu*mu;
    float is  = rsqrtf(var + BN_EPS);
    float a = is * gamma[c];
    float b = beta[c] - mu * a;
    A[c] = a; B[c] = b; Ash[c] = a; Bsh[c] = b;
    __syncthreads();
    if (hasNext){
        float bv = 0.f;
        for (int k = 0; k < 128; k++){
            float w = Wnext[k*128 + c];
            WpT[c*128 + k] = f2bf(Ash[k] * w);   // W'^T[n][k] = A[k]*W[k][n]
            bv = fmaf(Bsh[k], w, bv);
        }
        biasv[c] = bv;
    }
}

// ----------------- readout pooling (max, mean, first), bf16 in, BN applied inline -----------------
__global__ __launch_bounds__(1024) void k_pool(const unsigned short* __restrict__ X, const float* __restrict__ A,
                                               const float* __restrict__ B, float* __restrict__ g){
    __shared__ float shm[8][128];
    __shared__ float shs[8][128];
    int t = threadIdx.x;
    int c = t & 127, sl = t >> 7;    // 8 slices x 100 nodes
    int gr = blockIdx.x;
    float a = A[c], b = B[c];
    const unsigned short* base = X + ((size_t)gr*NPG + sl*100)*HID;
    float mx = -1e30f, sm = 0.f;
    for (int i = 0; i < 100; i++){
        float v = fmaf(bfu(base[(size_t)i*HID + c]), a, b);
        mx = fmaxf(mx, v); sm += v;
    }
    shm[sl][c] = mx; shs[sl][c] = sm;
    if (sl == 0) g[gr*384 + 256 + c] = fmaf(bfu(base[c]), a, b);   // first node
    __syncthreads();
    if (t < 128){
        float m = shm[0][t], s = shs[0][t];
        #pragma unroll
        for (int q = 1; q < 8; q++){ m = fmaxf(m, shm[q][t]); s += shs[q][t]; }
        g[gr*384 + t]       = m;
        g[gr*384 + 128 + t] = s * (1.0f/(float)NPG);
    }
}

// ----------------- MLP + log_softmax -----------------
__global__ __launch_bounds__(512) void k_mlp(const float* __restrict__ g, const float* __restrict__ W1,
                                             const float* __restrict__ b1, const float* __restrict__ W2,
                                             const float* __restrict__ b2, float* __restrict__ out){
    __shared__ float row[384];
    __shared__ float t1[384];
    __shared__ float r0[512], r1[512];
    int t = threadIdx.x, gr = blockIdx.x;
    if (t < 384) row[t] = g[gr*384 + t];
    __syncthreads();
    if (t < 384){
        float acc = b1[t];
        for (int k = 0; k < 384; k++) acc = fmaf(row[k], W1[(size_t)k*384 + t], acc);
        t1[t] = acc;
    }
    __syncthreads();
    float p0 = 0.f, p1 = 0.f;
    if (t < 384){ float v = t1[t]; p0 = v*W2[t*2]; p1 = v*W2[t*2+1]; }
    r0[t] = p0; r1[t] = p1; __syncthreads();
    for (int off = 256; off > 0; off >>= 1){
        if (t < off){ r0[t] += r0[t+off]; r1[t] += r1[t+off]; }
        __syncthreads();
    }
    if (t == 0){
        float o0 = r0[0] + b2[0], o1 = r1[0] + b2[1];
        float m = fmaxf(o0, o1);
        float lse = m + logf(expf(o0 - m) + expf(o1 - m));
        out[gr*2 + 0] = o0 - lse;
        out[gr*2 + 1] = o1 - lse;
    }
}

extern "C" void kernel_launch(void* const* d_in, const int* in_sizes, int n_in,
                              void* d_out, int out_size, void* d_ws, size_t ws_size,
                              hipStream_t stream){
    const float* x     = (const float*)d_in[0];
    const int*   ei    = (const int*)d_in[1];
    const float* Wconv = (const float*)d_in[3];
    const float* bconv = (const float*)d_in[4];
    const float* gamma = (const float*)d_in[5];
    const float* beta  = (const float*)d_in[6];
    const float* W1    = (const float*)d_in[7];
    const float* b1    = (const float*)d_in[8];
    const float* W2    = (const float*)d_in[9];
    const float* b2    = (const float*)d_in[10];
    float* out = (float*)d_out;

    char* p = (char*)d_ws;
    size_t off = 0;
    auto alloc = [&](size_t bytes)->char* {
        char* r = p + off; off += (bytes + 255) & ~(size_t)255; return r;
    };
    unsigned short* buf1 = (unsigned short*)alloc((size_t)(N_NODESC+1)*HID*2); // Hd (+1 dummy zero row)
    unsigned short* buf2 = (unsigned short*)alloc((size_t)N_NODESC*HID*2);     // post-agg relu'd bf16
    int*   srcS    = (int*)  alloc((size_t)N_EDGESC*4);
    int*   row_ptr = (int*)  alloc((size_t)(N_NODESC+1)*4);
    int*   deg     = (int*)  alloc((size_t)N_NODESC*4);      // reused as scatter cursor
    float* dinv    = (float*)alloc((size_t)N_NODESC*4);
    int*   chunkTot= (int*)  alloc(512);
    int*   chunkOff= (int*)  alloc(512);
    float* stats   = (float*)alloc(3*2*128*4);               // [l][sum|sumsq][128]
    float* AB      = (float*)alloc(3*2*128*4);               // [l][A|B][128]
    unsigned short* Wt0 = (unsigned short*)alloc(128*128*2); // bf16 W0^T
    unsigned short* WpT = (unsigned short*)alloc(128*128*2); // bf16 BN-folded next-layer W^T
    float* biasv   = (float*)alloc(512);
    float* g       = (float*)alloc((size_t)NUM_GRAPHS*384*4);
    (void)ws_size; (void)in_sizes; (void)n_in; (void)out_size;

    hipMemsetAsync(deg,   0, (size_t)N_NODESC*4, stream);
    hipMemsetAsync(stats, 0, 3*2*128*4, stream);
    hipMemsetAsync(biasv, 0, 512, stream);
    hipMemsetAsync(buf1 + (size_t)N_NODESC*HID, 0, HID*2, stream);  // dummy zero row

    k_count  <<<(N_EDGESC+255)/256, 256, 0, stream>>>(ei, deg);
    k_scan_a <<<N_NODESC/1024, 1024, 0, stream>>>(deg, row_ptr, dinv, chunkTot);
    k_scan_b <<<1, 128, 0, stream>>>(chunkTot, chunkOff, row_ptr);
    k_scan_c <<<N_NODESC/1024, 1024, 0, stream>>>(row_ptr, chunkOff);
    hipMemsetAsync(deg, 0, (size_t)N_NODESC*4, stream);      // cursor for scatter
    k_scatter<<<(N_EDGESC+255)/256, 256, 0, stream>>>(ei, row_ptr, deg, srcS);
    k_prepw0 <<<64, 256, 0, stream>>>(Wconv, Wt0);

    for (int l = 0; l < 3; l++){
        if (l == 0)
            k_gemm_mfma<1><<<N_NODESC/64, 256, 0, stream>>>((const void*)x, Wt0, biasv, dinv, buf1);
        else
            k_gemm_mfma<0><<<N_NODESC/64, 256, 0, stream>>>((const void*)buf2, WpT, biasv, dinv, buf1);
        k_agg<<<2048, 256, 0, stream>>>((const uint2*)buf1, row_ptr, srcS, dinv,
                                        bconv + l*HID, (uint2*)buf2,
                                        stats + l*256, stats + l*256 + 128);
        k_finalize<<<1, 128, 0, stream>>>(stats + l*256, stats + l*256 + 128,
                                          gamma + l*HID, beta + l*HID,
                                          Wconv + (size_t)(l+1 < 3 ? l+1 : 0)*HID*HID,
                                          AB + l*256, AB + l*256 + 128,
                                          WpT, biasv, (l < 2) ? 1 : 0);
    }
    k_pool<<<NUM_GRAPHS, 1024, 0, stream>>>(buf2, AB + 2*256, AB + 2*256 + 128, g);
    k_mlp <<<NUM_GRAPHS, 512, 0, stream>>>(g, W1, b1, W2, b2, out);
}